// Round 3
// baseline (706.681 us; speedup 1.0000x reference)
//
#include <hip/hip_runtime.h>
#include <math.h>

#define PI2 6.28318530717958647692f

// Problem constants: B=32, CI=CO=64, H=W=128, M1=M2=32.
// Slot convention: slot kxi in [0,64): kx = kxi (kxi<32) or kxi+64 (kxi>=32).
// Workspace (float2, interleaved complex):
//   Xf [bi=2048][kxi=64][ky=32]   (ws + 0)
//   T  [bo=2048][kxi=64][ky=32]   (ws + 4194304)
// out [b=32][o=64][h=128][w'=65] fp32

// ================= Fused forward: x -> Xf (row DFT then col DFT) =============
// Block = one (b, ci) image. 256 threads. 4 quarters of 32 h-rows.
// LDS: xs 16 KB (swizzled) + ys 8 KB + E-table 16 KB = 40 KB -> 4 blocks/CU.
// E[a][b] = e^{-2pi i a b / 128}, a<64, b<32: shared by row-DFT (w,ky) and
// col-DFT (h,kxi). Radix-2 pairings:
//   row:  Y[ky]   = sum_{w<64} (x[w] + (-1)^ky x[w+64]) E[w][ky]
//   col:  slot p+32 factor = i^h * E[h][p];  h>=64: E[h][p] = (-1)^p E[h-64][p]
__global__ __launch_bounds__(256) void k_fwd(const float* __restrict__ x,
                                             float2* __restrict__ xf) {
    __shared__ float xs[32 * 128];   // quarter rows, column-rotated by 4*hl
    __shared__ float2 ys[32 * 32];   // Y quarter [hl][ky]
    __shared__ float2 E[64 * 32];    // e^{-2pi i a b/128}
    const int bi = blockIdx.x;
    const int t = threadIdx.x;
    const float* xp = x + (size_t)bi * 16384;

    // Build twiddle table (angle reduced mod 128 for accuracy).
    for (int idx = t; idx < 2048; idx += 256) {
        int a = idx >> 5, b = idx & 31;
        int r = (a * b) & 127;
        float sv, cv;
        sincosf(-PI2 * (float)r / 128.0f, &sv, &cv);
        E[idx] = make_float2(cv, sv);
    }

    // Thread roles (same decomposition for B and C phases):
    const int kyq = t & 7;          // ky0 = 4*kyq
    const int p   = t >> 3;         // 0..31: B: local row hl; C: slot pair (p, p+32)
    const int ky0 = kyq * 4;

    // Col-DFT accumulators, persist across quarters.
    float2 accB[4], accP[4];
#pragma unroll
    for (int j = 0; j < 4; j++) { accB[j] = make_float2(0.f, 0.f); accP[j] = make_float2(0.f, 0.f); }
    const float sgnOdd = (p & 1) ? -1.0f : 1.0f;  // for h >= 64 rows

    for (int q = 0; q < 4; q++) {
        // ---- Stage quarter rows 32q..32q+31 into xs (rotated by 4*hl) ----
        for (int idx = t * 4; idx < 4096; idx += 1024) {
            int hl = idx >> 7, w = idx & 127;
            float4 v = *(const float4*)&xp[(32 * q + hl) * 128 + w];
            int wr = (w + 4 * hl) & 127;  // w mult of 4, rotation mult of 4: no straddle
            float* d = &xs[(hl << 7) + wr];
            d[0] = v.x; d[1] = v.y; d[2] = v.z; d[3] = v.w;
        }
        __syncthreads();

        // ---- B phase: row DFT, thread = 1 hl x 4 ky ----
        {
            const int hl = p;
            float2 a0 = make_float2(0.f,0.f), a1 = a0, a2 = a0, a3 = a0;
            const float* xrow = &xs[hl << 7];
            int wp = (4 * hl) & 127;
#pragma unroll 4
            for (int w = 0; w < 64; w++) {
                float xe = xrow[wp];
                float xo = xrow[wp ^ 64];
                wp = (wp + 1) & 127;
                float xve = xe + xo, xvo = xe - xo;
                const float2* tw = &E[(w << 5) + ky0];
                float2 t0 = tw[0], t1 = tw[1], t2 = tw[2], t3 = tw[3];
                a0.x += xve * t0.x; a0.y += xve * t0.y;
                a1.x += xvo * t1.x; a1.y += xvo * t1.y;
                a2.x += xve * t2.x; a2.y += xve * t2.y;
                a3.x += xvo * t3.x; a3.y += xvo * t3.y;
            }
            float2* yo = &ys[(hl << 5) + ky0];
            yo[0] = a0; yo[1] = a1; yo[2] = a2; yo[3] = a3;
        }
        __syncthreads();

        // ---- C phase: col DFT partial over this quarter's 32 rows ----
        {
            const float sgn = (q >= 2) ? sgnOdd : 1.0f;
#pragma unroll
            for (int hl = 0; hl < 32; hl += 4) {
#pragma unroll
                for (int u = 0; u < 4; u++) {
                    const int h = hl + u;
                    float2 tw = E[(((h + 32 * q) & 63) << 5) + p];
                    float twr = sgn * tw.x, twi = sgn * tw.y;
                    // pair coeff = i^h * (twr, twi), h mod 4 == u mod 4 (static):
                    float pr, pi;
                    if (u == 0)      { pr = twr;  pi = twi;  }
                    else if (u == 1) { pr = -twi; pi = twr;  }
                    else if (u == 2) { pr = -twr; pi = -twi; }
                    else             { pr = twi;  pi = -twr; }
                    const float2* yv = &ys[(h << 5) + ky0];
#pragma unroll
                    for (int j = 0; j < 4; j++) {
                        float2 yj = yv[j];
                        accB[j].x += twr * yj.x - twi * yj.y;
                        accB[j].y += twr * yj.y + twi * yj.x;
                        accP[j].x += pr * yj.x - pi * yj.y;
                        accP[j].y += pr * yj.y + pi * yj.x;
                    }
                }
            }
        }
        __syncthreads();  // guards xs overwrite (next stage) & ys reuse
    }

    // ---- Write Xf: slots p and p+32 ----
    float2* xo = xf + (size_t)bi * 2048;
#pragma unroll
    for (int j = 0; j < 4; j++) xo[(p << 5) + ky0 + j] = accB[j];
#pragma unroll
    for (int j = 0; j < 4; j++) xo[((p + 32) << 5) + ky0 + j] = accP[j];
}

// ---------------- Stage M: channel mix, T = Xf @ conj(W) (unchanged) --------
__global__ __launch_bounds__(512) void k_mix(const float2* __restrict__ xf,
                                             const float* __restrict__ w1r, const float* __restrict__ w1i,
                                             const float* __restrict__ w2r, const float* __restrict__ w2i,
                                             float2* __restrict__ tt) {
    __shared__ float2 xfs[8192];  // [8 b][32 i][32 ky] per stage, 64 KiB
    const int kxi = blockIdx.x;       // 0..63
    const int b0 = blockIdx.y * 8;    // 4 groups of 8 b
    const int t = threadIdx.x;
    const int ky = t & 31, grp = t >> 5;  // grp 0..15
    const int o0 = grp * 4;
    const float* wr = (kxi < 32) ? w1r : w2r;
    const float* wi = (kxi < 32) ? w1i : w2i;
    const int kxim = kxi & 31;
    float accr[8][4], acci[8][4];
    for (int jb = 0; jb < 8; jb++)
        for (int jo = 0; jo < 4; jo++) { accr[jb][jo] = 0.0f; acci[jb][jo] = 0.0f; }

    for (int stage = 0; stage < 2; stage++) {
        const int ibase = stage * 32;
        __syncthreads();
        for (int idx = t; idx < 8192; idx += 512) {
            int b = idx >> 10, ii = (idx >> 5) & 31, kk = idx & 31;
            size_t g = ((size_t)(b0 + b) * 64 + (ibase + ii)) * 2048 + (size_t)kxi * 32 + kk;
            xfs[idx] = xf[g];
        }
        __syncthreads();
        for (int ii = 0; ii < 32; ii++) {
            const int i = ibase + ii;
            float wr4[4], wi4[4];
#pragma unroll
            for (int jo = 0; jo < 4; jo++) {
                size_t g = ((size_t)i * 64 + (o0 + jo)) * 1024 + (size_t)kxim * 32 + ky;
                wr4[jo] = wr[g]; wi4[jo] = wi[g];
            }
#pragma unroll
            for (int jb = 0; jb < 8; jb++) {
                float2 xv = xfs[(jb << 10) + (ii << 5) + ky];
#pragma unroll
                for (int jo = 0; jo < 4; jo++) {
                    accr[jb][jo] += xv.x * wr4[jo] + xv.y * wi4[jo];
                    acci[jb][jo] += xv.y * wr4[jo] - xv.x * wi4[jo];
                }
            }
        }
    }
    for (int jb = 0; jb < 8; jb++)
        for (int jo = 0; jo < 4; jo++) {
            size_t g = ((size_t)(b0 + jb) * 64 + (o0 + jo)) * 2048 + (size_t)kxi * 32 + ky;
            tt[g] = make_float2(accr[jb][jo], acci[jb][jo]);
        }
}

// ================= Fused inverse: T -> out (I1 then I2, Z stays in LDS) =====
// Block = one (b, o) image. 256 threads.
// LDS: ts [32 ky][64+2 kxi] 16.5 KB + zs [64 kxi][65+3 w] 34.8 KB -> 3 blocks/CU.
// I1: Z[kxi][w] = sum_ky T[kxi][ky] e^{+2pi i ky w/65} (twiddle shared by 16 kxi)
// I2: out[h][w]    = (E+O)/N,  out[h+64][w] = (E-O)/N, where
//     E/O = Re sum_{kxi even/odd} e^{2pi i kxi h/128} (z1 + (-i)^h z2)
__global__ __launch_bounds__(256) void k_inv(const float2* __restrict__ tt,
                                             float* __restrict__ out) {
    __shared__ float2 ts[32 * 66];
    __shared__ float2 zs[64 * 68];
    const int bo = blockIdx.x, t = threadIdx.x;
    const float2* tp = tt + (size_t)bo * 2048;
    for (int idx = t; idx < 2048; idx += 256) {
        int kxi = idx >> 5, ky = idx & 31;
        ts[ky * 66 + kxi] = tp[idx];     // transposed for broadcast column reads
    }
    for (int idx = t; idx < 64 * 3; idx += 256) {   // zero the w-pad columns
        int kxi = idx / 3, w = 65 + idx % 3;
        zs[kxi * 68 + w] = make_float2(0.f, 0.f);
    }
    __syncthreads();

    // ---- I1: items = 65 w x 4 groups of 16 kxi ----
    for (int pp = t; pp < 260; pp += 256) {
        int w = pp % 65, g = pp / 65;
        const int kx0 = g * 16;
        float dcc, dss;
        sincosf(PI2 * (float)w / 65.0f, &dss, &dcc);
        float c = 1.f, s = 0.f;
        float2 acc[16];
#pragma unroll
        for (int j = 0; j < 16; j++) acc[j] = make_float2(0.f, 0.f);
        for (int ky = 0; ky < 32; ky++) {
            const float2* tv = &ts[ky * 66 + kx0];
#pragma unroll
            for (int j = 0; j < 16; j++) {
                float2 v = tv[j];
                acc[j].x += v.x * c - v.y * s;
                acc[j].y += v.x * s + v.y * c;
            }
            float nc = c * dcc - s * dss;
            s = s * dcc + c * dss;
            c = nc;
        }
#pragma unroll
        for (int j = 0; j < 16; j++) zs[(kx0 + j) * 68 + w] = acc[j];
    }
    __syncthreads();

    // ---- I2: thread = (hb = t>>2 in 0..63, wq = t&3); tiles of 4 w ----
    const int hb = t >> 2, wq = t & 3;
    float dcc, dss;
    sincosf(PI2 * (float)hb / 128.0f, &dss, &dcc);
    const int m = hb & 3;   // f = (-i)^hb
    const float fr = (m == 0) ? 1.f : (m == 2) ? -1.f : 0.f;
    const float fi = (m == 1) ? -1.f : (m == 3) ? 1.f : 0.f;
    const float scale = 1.0f / 8320.0f;   // 1/(128*65)
    float* op = out + (size_t)bo * 8320;

    for (int pass = 0; pass < 5; pass++) {
        const int tile = wq + 4 * pass;
        if (tile <= 16) {
            const int w0 = tile * 4;
            float c = 1.f, s = 0.f;
            float Er[4] = {0.f,0.f,0.f,0.f}, Or[4] = {0.f,0.f,0.f,0.f};
            for (int kxi = 0; kxi < 32; kxi += 2) {
#pragma unroll
                for (int u = 0; u < 2; u++) {
                    const float2* p1 = &zs[(kxi + u) * 68 + w0];
                    const float2* p2 = &zs[(kxi + u + 32) * 68 + w0];
#pragma unroll
                    for (int k = 0; k < 4; k++) {
                        float2 z1 = p1[k], z2 = p2[k];
                        float ar = z1.x + fr * z2.x - fi * z2.y;
                        float ai = z1.y + fr * z2.y + fi * z2.x;
                        float v = c * ar - s * ai;
                        if (u == 0) Er[k] += v; else Or[k] += v;
                    }
                    float nc = c * dcc - s * dss;
                    s = s * dcc + c * dss;
                    c = nc;
                }
            }
#pragma unroll
            for (int k = 0; k < 4; k++) {
                int w = w0 + k;
                if (w < 65) {
                    op[hb * 65 + w]        = (Er[k] + Or[k]) * scale;
                    op[(hb + 64) * 65 + w] = (Er[k] - Or[k]) * scale;
                }
            }
        }
    }
}

extern "C" void kernel_launch(void* const* d_in, const int* in_sizes, int n_in,
                              void* d_out, int out_size, void* d_ws, size_t ws_size,
                              hipStream_t stream) {
    const float* x   = (const float*)d_in[0];
    const float* w1r = (const float*)d_in[1];
    const float* w1i = (const float*)d_in[2];
    const float* w2r = (const float*)d_in[3];
    const float* w2i = (const float*)d_in[4];
    float2* ws = (float2*)d_ws;

    float2* xfa = ws;             // 4,194,304 float2
    float2* ta  = ws + 4194304;   // 4,194,304 float2
    float* out = (float*)d_out;

    k_fwd<<<2048, 256, 0, stream>>>(x, xfa);
    k_mix<<<dim3(64, 4), 512, 0, stream>>>(xfa, w1r, w1i, w2r, w2i, ta);
    k_inv<<<2048, 256, 0, stream>>>(ta, out);
}